// Round 11
// baseline (609.835 us; speedup 1.0000x reference)
//
#include <hip/hip_runtime.h>
#include <math.h>

#define NN 100000
#define EE 1200000
#define DD 64
#define GG 1024
#define LL 3
#define VOCAB 128
#define SCAN_NB 98     // ceil(100000/1024)
#define PSTR 64        // padded CSR row stride (slots/node); Poisson(12) max-deg << 64
#define FILL_NB 2048   // fill grid: 8 blocks/CU

// ---------------- encoder: h[n][j] = sum_f emb[f][x_atom[n][f]][j] ----------------
__global__ __launch_bounds__(256) void enc_kernel(const int* __restrict__ x_atom,
                                                  const float* __restrict__ emb,
                                                  float* __restrict__ h) {
    int idx = blockIdx.x * 256 + threadIdx.x;      // n*64 + j
    if (idx >= NN * 64) return;
    int n = idx >> 6, j = idx & 63;
    int v0 = x_atom[n * 3 + 0];
    int v1 = x_atom[n * 3 + 1];
    int v2 = x_atom[n * 3 + 2];
    h[idx] = emb[(0 * VOCAB + v0) * 64 + j]
           + emb[(1 * VOCAB + v1) * 64 + j]
           + emb[(2 * VOCAB + v2) * 64 + j];
}

// ---------------- init: hist=0, fill=0 ----------------
__global__ __launch_bounds__(256) void init_kernel(int* __restrict__ hist,
                                                   int* __restrict__ fill) {
    int i = blockIdx.x * 256 + threadIdx.x;
    if (i < NN) { hist[i] = 0; fill[i] = 0; }
}

// ---------------- in-degree histogram (compact fallback path only) ----------------
__global__ __launch_bounds__(256) void hist_kernel(const int* __restrict__ ei,
                                                   int* __restrict__ hist) {
    int e = blockIdx.x * 256 + threadIdx.x;
    if (e >= EE) return;
    atomicAdd(&hist[ei[EE + e]], 1);
}

// ---------------- scan stage 1 (fallback) ----------------
__global__ __launch_bounds__(256) void scan1_kernel(const int* __restrict__ hist,
                                                    int* __restrict__ bsum) {
    __shared__ int sd[256];
    int t = threadIdx.x, b = blockIdx.x;
    int base = b * 1024 + t * 4;
    int s = 0;
#pragma unroll
    for (int u = 0; u < 4; ++u) { int i = base + u; if (i < NN) s += hist[i]; }
    sd[t] = s;
    __syncthreads();
    for (int off = 128; off > 0; off >>= 1) {
        if (t < off) sd[t] += sd[t + off];
        __syncthreads();
    }
    if (t == 0) bsum[b] = sd[0];
}

// ---------------- scan stage 2 (fallback) ----------------
__global__ void scan2_kernel(const int* __restrict__ bsum, int* __restrict__ boff,
                             int* __restrict__ rowst) {
    if (threadIdx.x == 0 && blockIdx.x == 0) {
        int acc = 0;
        for (int i = 0; i < SCAN_NB; ++i) { boff[i] = acc; acc += bsum[i]; }
        rowst[NN] = acc;   // == EE
    }
}

// ---------------- scan stage 3 (fallback) ----------------
__global__ __launch_bounds__(256) void scan3_kernel(const int* __restrict__ hist,
                                                    const int* __restrict__ boff,
                                                    int* __restrict__ rowst) {
    __shared__ int sd[256];
    int t = threadIdx.x, b = blockIdx.x;
    int base = b * 1024 + t * 4;
    int v[4]; int s = 0;
#pragma unroll
    for (int u = 0; u < 4; ++u) {
        int i = base + u;
        v[u] = (i < NN) ? hist[i] : 0;
        s += v[u];
    }
    sd[t] = s;
    __syncthreads();
    for (int off = 1; off < 256; off <<= 1) {
        int a = (t >= off) ? sd[t - off] : 0;
        __syncthreads();
        sd[t] += a;
        __syncthreads();
    }
    int texcl = sd[t] - s;
    int o = boff[b] + texcl;
#pragma unroll
    for (int u = 0; u < 4; ++u) {
        int i = base + u;
        if (i < NN) rowst[i] = o;
        o += v[u];
    }
}

// ---------------- CSR fill: direct 16B pack scatter (known wall ~84us) ----------------
__global__ __launch_bounds__(256) void fill_kernel(const int* __restrict__ ei,
                                                   const float* __restrict__ ea,
                                                   const int* __restrict__ rowst,
                                                   int* __restrict__ fill,
                                                   float4* __restrict__ pack,
                                                   int padded) {
    const int T = FILL_NB * 256;                 // 524288 threads total
    int t0 = blockIdx.x * 256 + threadIdx.x;
    int e[3] = { t0, t0 + T, t0 + 2 * T };
    int d[3]; float4 p[3]; bool v[3];
#pragma unroll
    for (int u = 0; u < 3; ++u) {
        v[u] = (e[u] < EE);
        if (v[u]) {
            int s = ei[e[u]];
            d[u] = ei[EE + e[u]];
            p[u].x = ea[e[u] * 3 + 0];
            p[u].y = ea[e[u] * 3 + 1];
            p[u].z = ea[e[u] * 3 + 2];
            p[u].w = __int_as_float(s);
        }
    }
    int pos[3];
#pragma unroll
    for (int u = 0; u < 3; ++u)
        if (v[u]) pos[u] = atomicAdd(&fill[d[u]], 1);
#pragma unroll
    for (int u = 0; u < 3; ++u) {
        if (v[u]) {
            if (padded) {
                if (pos[u] < PSTR) pack[((size_t)d[u] << 6) + pos[u]] = p[u];
            } else {
                pack[rowst[d[u]] + pos[u]] = p[u];
            }
        }
    }
}

// ---------------- weighted degree: 16-lane group per node, parallel row-sum ----------------
__global__ __launch_bounds__(256) void degdinv_kernel(const float4* __restrict__ pack,
                                                      const int* __restrict__ rowst,
                                                      const int* __restrict__ cnt,
                                                      float* __restrict__ dinv,
                                                      int padded) {
    int n   = (blockIdx.x * 256 + threadIdx.x) >> 4;
    int sub = threadIdx.x & 15;
    if (n >= NN) return;
    int s0 = padded ? (n << 6) : rowst[n];
    int c  = padded ? min(cnt[n], PSTR) : (rowst[n + 1] - rowst[n]);
    float d0 = 0.f, d1 = 0.f, d2 = 0.f;
    for (int s = sub; s < c; s += 16) {
        float4 p = pack[s0 + s];
        d0 += p.x; d1 += p.y; d2 += p.z;
    }
#pragma unroll
    for (int off = 8; off > 0; off >>= 1) {
        d0 += __shfl_down(d0, off, 16);
        d1 += __shfl_down(d1, off, 16);
        d2 += __shfl_down(d2, off, 16);
    }
    if (sub == 0) {
        d0 += 1.0f; d1 += 1.0f; d2 += 1.0f;   // self-loop weight 1
        dinv[n]          = 1.0f / sqrtf(d0);
        dinv[NN + n]     = 1.0f / sqrtf(d1);
        dinv[2 * NN + n] = 1.0f / sqrtf(d2);
    }
}

// ---------------- fold SOURCE-side dinv into pack (dst side applied in agg) ----------------
__global__ __launch_bounds__(256) void normpack_kernel(const float* __restrict__ dinv,
                                                       const int* __restrict__ rowst,
                                                       const int* __restrict__ cnt,
                                                       float4* __restrict__ pack,
                                                       int padded) {
    int n   = (blockIdx.x * 256 + threadIdx.x) >> 4;
    int sub = threadIdx.x & 15;
    if (n >= NN) return;
    int s0 = padded ? (n << 6) : rowst[n];
    int c  = padded ? min(cnt[n], PSTR) : (rowst[n + 1] - rowst[n]);
    for (int s = sub; s < c; s += 16) {
        float4 p = pack[s0 + s];
        int src = __float_as_int(p.w);
        p.x *= dinv[src];
        p.y *= dinv[NN + src];
        p.z *= dinv[2 * NN + src];
        pack[s0 + s] = p;
    }
}

// ---------------- aggregation: one wave per node, depth-16 masked batches ----------------
// Poisson(12) deg => one 16-deep batch covers 89% of rows in a single latency round.
// Outstanding gathers/CU = waves x 16 is the lever (R10 lesson: occupancy x depth).
__global__ __launch_bounds__(256) void agg_kernel(const float* __restrict__ h,
                                                  const float4* __restrict__ pack,
                                                  const int* __restrict__ rowst,
                                                  const int* __restrict__ cnt,
                                                  const float* __restrict__ dinv,
                                                  float* __restrict__ agg,
                                                  int padded) {
    int n = (blockIdx.x * 256 + threadIdx.x) >> 6;
    int lane = threadIdx.x & 63;
    if (n >= NN) return;
    float d0 = dinv[n], d1 = dinv[NN + n], d2 = dinv[2 * NN + n];
    float hs = h[(size_t)n * 64 + lane];
    float a0 = hs * d0;     // self-loop: src-side factor = dinv_k[n]
    float a1 = hs * d1;
    float a2 = hs * d2;
    int s0 = padded ? (n << 6) : rowst[n];
    int s1 = s0 + (padded ? min(cnt[n], PSTR) : (rowst[n + 1] - rowst[n]));
    for (int s = s0; s < s1; s += 16) {
        float4 p[16];
#pragma unroll
        for (int u = 0; u < 16; ++u) {
            int idx = s + u;
            p[u] = pack[(idx < s1) ? idx : s0];
        }
        float hv[16];
#pragma unroll
        for (int u = 0; u < 16; ++u)
            hv[u] = h[(size_t)__float_as_int(p[u].w) * 64 + lane];
#pragma unroll
        for (int u = 0; u < 16; ++u) {
            float m = (s + u < s1) ? 1.f : 0.f;
            a0 = fmaf(hv[u], p[u].x * m, a0);
            a1 = fmaf(hv[u], p[u].y * m, a1);
            a2 = fmaf(hv[u], p[u].z * m, a2);
        }
    }
    agg[(size_t)n * 192 + lane]       = a0 * d0;
    agg[(size_t)n * 192 + 64 + lane]  = a1 * d1;
    agg[(size_t)n * 192 + 128 + lane] = a2 * d2;
}

// ---------------- fused GEMM: h_new = relu?(agg[N,192]@Wcat[192,64] + bsum) + h ----------------
__global__ __launch_bounds__(256) void gemm_kernel(const float* __restrict__ agg,
                                                   const float* __restrict__ convW,
                                                   const float* __restrict__ convb,
                                                   float* __restrict__ h,
                                                   int layer, int dorelu) {
    __shared__ float an[64][68];    // agg chunk [node][k]   (+pad)
    __shared__ float ws[64][64];    // W chunk   [k][col]
    int t = threadIdx.x;
    int n0 = blockIdx.x * 64;
    const float* W = convW + (size_t)layer * 192 * 64;
    const float* B = convb + (size_t)layer * 192;
    int nb = t >> 4, cb = t & 15;
    float acc[4][4] = {{0.f}};

    for (int kc = 0; kc < 3; ++kc) {
        __syncthreads();
#pragma unroll
        for (int rep = 0; rep < 16; ++rep) {
            int flat = rep * 256 + t;        // 0..4095
            int r = flat >> 6, i = flat & 63;
            int n = n0 + r;
            an[r][i] = (n < NN) ? agg[(size_t)n * 192 + kc * 64 + i] : 0.f;
            ((float*)ws)[flat] = W[kc * 4096 + flat];
        }
        __syncthreads();
#pragma unroll 4
        for (int i = 0; i < 64; ++i) {
            float4 wv = *(const float4*)&ws[i][cb * 4];
#pragma unroll
            for (int r = 0; r < 4; ++r) {
                float a = an[nb * 4 + r][i];
                acc[r][0] = fmaf(a, wv.x, acc[r][0]);
                acc[r][1] = fmaf(a, wv.y, acc[r][1]);
                acc[r][2] = fmaf(a, wv.z, acc[r][2]);
                acc[r][3] = fmaf(a, wv.w, acc[r][3]);
            }
        }
    }

    int col0 = cb * 4;
    float bs[4];
#pragma unroll
    for (int c = 0; c < 4; ++c) {
        int col = col0 + c;
        bs[c] = B[col] + B[64 + col] + B[128 + col];
    }
#pragma unroll
    for (int r = 0; r < 4; ++r) {
        int n = n0 + nb * 4 + r;
        if (n < NN) {
            float4 hv = *(const float4*)&h[(size_t)n * 64 + col0];
            float v0 = acc[r][0] + bs[0];
            float v1 = acc[r][1] + bs[1];
            float v2 = acc[r][2] + bs[2];
            float v3 = acc[r][3] + bs[3];
            if (dorelu) {
                v0 = fmaxf(v0, 0.f); v1 = fmaxf(v1, 0.f);
                v2 = fmaxf(v2, 0.f); v3 = fmaxf(v3, 0.f);
            }
            float4 o;
            o.x = v0 + hv.x; o.y = v1 + hv.y; o.z = v2 + hv.z; o.w = v3 + hv.w;
            *(float4*)&h[(size_t)n * 64 + col0] = o;
        }
    }
}

// ---------------- graph start offsets via binary search (batch is sorted) ----------------
__global__ __launch_bounds__(256) void gstart_kernel(const int* __restrict__ batch,
                                                     int* __restrict__ gstart) {
    int g = blockIdx.x * 256 + threadIdx.x;
    if (g > GG) return;
    int lo = 0, hi = NN;
    while (lo < hi) {
        int mid = (lo + hi) >> 1;
        if (batch[mid] < g) lo = mid + 1; else hi = mid;
    }
    gstart[g] = lo;
}

// ---------------- mean pool: one block (4 waves) per graph ----------------
__global__ __launch_bounds__(256) void pool_kernel(const float* __restrict__ h,
                                                   const int* __restrict__ gstart,
                                                   float* __restrict__ hg) {
    __shared__ float red[3][64];
    int g = blockIdx.x;
    int w = threadIdx.x >> 6, lane = threadIdx.x & 63;
    int s = gstart[g], e = gstart[g + 1];
    float sum = 0.f;
    for (int n = s + w; n < e; n += 4) sum += h[(size_t)n * 64 + lane];
    if (w) red[w - 1][lane] = sum;
    __syncthreads();
    if (w == 0) {
        sum += red[0][lane] + red[1][lane] + red[2][lane];
        int c = e - s;
        hg[(size_t)g * 64 + lane] = sum / (float)(c > 0 ? c : 1);
    }
}

// ---------------- fc: 3 stacked linears, one wave per graph ----------------
__global__ __launch_bounds__(256) void fc_kernel(const float* __restrict__ hg,
                                                 const float* __restrict__ W1, const float* __restrict__ b1,
                                                 const float* __restrict__ W2, const float* __restrict__ b2,
                                                 const float* __restrict__ W3, const float* __restrict__ b3,
                                                 float* __restrict__ out) {
    int g = (blockIdx.x * 256 + threadIdx.x) >> 6;
    int lane = threadIdx.x & 63;
    if (g >= GG) return;
    float x = hg[(size_t)g * 64 + lane];
    float t1 = b1[lane];
    for (int i = 0; i < 64; ++i) t1 = fmaf(__shfl(x, i, 64), W1[i * 64 + lane], t1);
    float t2 = b2[lane];
    for (int i = 0; i < 64; ++i) t2 = fmaf(__shfl(t1, i, 64), W2[i * 64 + lane], t2);
    float p = t2 * W3[lane];
    for (int off = 32; off > 0; off >>= 1) p += __shfl_down(p, off, 64);
    if (lane == 0) out[g] = p + b3[0];
}

extern "C" void kernel_launch(void* const* d_in, const int* in_sizes, int n_in,
                              void* d_out, int out_size, void* d_ws, size_t ws_size,
                              hipStream_t stream) {
    const int*   x_atom = (const int*)d_in[0];
    const int*   ei     = (const int*)d_in[1];
    const float* ea     = (const float*)d_in[2];
    const int*   batch  = (const int*)d_in[3];
    const float* emb    = (const float*)d_in[4];
    const float* convW  = (const float*)d_in[5];
    const float* convb  = (const float*)d_in[6];
    const float* W1 = (const float*)d_in[7];  const float* b1 = (const float*)d_in[8];
    const float* W2 = (const float*)d_in[9];  const float* b2 = (const float*)d_in[10];
    const float* W3 = (const float*)d_in[11]; const float* b3 = (const float*)d_in[12];
    float* out = (float*)d_out;

    char* p = (char*)d_ws;
    size_t used = 0;
    auto alloc = [&](size_t bytes) -> void* {
        void* r = (void*)p;
        size_t rb = (bytes + 255) & ~(size_t)255;
        p += rb; used += rb;
        return r;
    };
    float*  h     = (float*)alloc((size_t)NN * 64 * 4);       // 25.6 MB
    float*  agg   = (float*)alloc((size_t)NN * 192 * 4);      // 76.8 MB
    float*  dinv  = (float*)alloc((size_t)3 * NN * 4);        // 1.2 MB
    int*    hist  = (int*)alloc((size_t)NN * 4);
    int*    rowst = (int*)alloc((size_t)(NN + 1) * 4);
    int*    fill  = (int*)alloc((size_t)NN * 4);
    int*    bsum  = (int*)alloc(128 * 4);
    int*    boff  = (int*)alloc(128 * 4);
    int*    gstart= (int*)alloc((size_t)(GG + 1) * 4);
    float*  hg    = (float*)alloc((size_t)GG * 64 * 4);
    // pack last: padded (102.4 MB) if workspace allows, else compact (19.2 MB, +16 slot margin)
    size_t padded_pack  = (size_t)NN * PSTR * 16;
    size_t compact_pack = (size_t)(EE + 16) * 16;
    int padded = (ws_size >= used + padded_pack) ? 1 : 0;
    float4* pack = (float4*)alloc(padded ? padded_pack : compact_pack);

    // ---- encoder + CSR build ----
    enc_kernel<<<(NN * 64) / 256, 256, 0, stream>>>(x_atom, emb, h);
    init_kernel<<<(NN + 255) / 256, 256, 0, stream>>>(hist, fill);
    if (!padded) {
        hist_kernel<<<(EE + 255) / 256, 256, 0, stream>>>(ei, hist);
        scan1_kernel<<<SCAN_NB, 256, 0, stream>>>(hist, bsum);
        scan2_kernel<<<1, 64, 0, stream>>>(bsum, boff, rowst);
        scan3_kernel<<<SCAN_NB, 256, 0, stream>>>(hist, boff, rowst);
    }
    fill_kernel<<<FILL_NB, 256, 0, stream>>>(ei, ea, rowst, fill, pack, padded);
    degdinv_kernel<<<(NN * 16 + 255) / 256, 256, 0, stream>>>(pack, rowst, fill, dinv, padded);
    normpack_kernel<<<(NN * 16 + 255) / 256, 256, 0, stream>>>(dinv, rowst, fill, pack, padded);
    gstart_kernel<<<(GG + 1 + 255) / 256, 256, 0, stream>>>(batch, gstart);

    // ---- 3 GCN layers: aggregate-then-GEMM (linearity refactor) ----
    for (int layer = 0; layer < LL; ++layer) {
        agg_kernel<<<NN / 4, 256, 0, stream>>>(h, pack, rowst, fill, dinv, agg, padded);
        gemm_kernel<<<(NN + 63) / 64, 256, 0, stream>>>(agg, convW, convb, h, layer,
                                                        (layer < LL - 1) ? 1 : 0);
    }

    // ---- pool + fc ----
    pool_kernel<<<GG, 256, 0, stream>>>(h, gstart, hg);
    fc_kernel<<<GG / 4, 256, 0, stream>>>(hg, W1, b1, W2, b2, W3, b3, out);
}

// Round 12
// 487.914 us; speedup vs baseline: 1.2499x; 1.2499x over previous
//
#include <hip/hip_runtime.h>
#include <math.h>

#define NN 100000
#define EE 1200000
#define DD 64
#define GG 1024
#define LL 3
#define VOCAB 128
#define SCAN_NB 98     // ceil(100000/1024)
#define PSTR 64        // padded CSR row stride (slots/node); Poisson(12) max-deg << 64
#define FILL_NB 2048   // fill grid: 8 blocks/CU

// ---------------- encoder: h[n][j] = sum_f emb[f][x_atom[n][f]][j] ----------------
__global__ __launch_bounds__(256) void enc_kernel(const int* __restrict__ x_atom,
                                                  const float* __restrict__ emb,
                                                  float* __restrict__ h) {
    int idx = blockIdx.x * 256 + threadIdx.x;      // n*64 + j
    if (idx >= NN * 64) return;
    int n = idx >> 6, j = idx & 63;
    int v0 = x_atom[n * 3 + 0];
    int v1 = x_atom[n * 3 + 1];
    int v2 = x_atom[n * 3 + 2];
    h[idx] = emb[(0 * VOCAB + v0) * 64 + j]
           + emb[(1 * VOCAB + v1) * 64 + j]
           + emb[(2 * VOCAB + v2) * 64 + j];
}

// ---------------- init: hist=0, fill=0 ----------------
__global__ __launch_bounds__(256) void init_kernel(int* __restrict__ hist,
                                                   int* __restrict__ fill) {
    int i = blockIdx.x * 256 + threadIdx.x;
    if (i < NN) { hist[i] = 0; fill[i] = 0; }
}

// ---------------- in-degree histogram (compact fallback path only) ----------------
__global__ __launch_bounds__(256) void hist_kernel(const int* __restrict__ ei,
                                                   int* __restrict__ hist) {
    int e = blockIdx.x * 256 + threadIdx.x;
    if (e >= EE) return;
    atomicAdd(&hist[ei[EE + e]], 1);
}

// ---------------- scan stage 1 (fallback) ----------------
__global__ __launch_bounds__(256) void scan1_kernel(const int* __restrict__ hist,
                                                    int* __restrict__ bsum) {
    __shared__ int sd[256];
    int t = threadIdx.x, b = blockIdx.x;
    int base = b * 1024 + t * 4;
    int s = 0;
#pragma unroll
    for (int u = 0; u < 4; ++u) { int i = base + u; if (i < NN) s += hist[i]; }
    sd[t] = s;
    __syncthreads();
    for (int off = 128; off > 0; off >>= 1) {
        if (t < off) sd[t] += sd[t + off];
        __syncthreads();
    }
    if (t == 0) bsum[b] = sd[0];
}

// ---------------- scan stage 2 (fallback) ----------------
__global__ void scan2_kernel(const int* __restrict__ bsum, int* __restrict__ boff,
                             int* __restrict__ rowst) {
    if (threadIdx.x == 0 && blockIdx.x == 0) {
        int acc = 0;
        for (int i = 0; i < SCAN_NB; ++i) { boff[i] = acc; acc += bsum[i]; }
        rowst[NN] = acc;   // == EE
    }
}

// ---------------- scan stage 3 (fallback) ----------------
__global__ __launch_bounds__(256) void scan3_kernel(const int* __restrict__ hist,
                                                    const int* __restrict__ boff,
                                                    int* __restrict__ rowst) {
    __shared__ int sd[256];
    int t = threadIdx.x, b = blockIdx.x;
    int base = b * 1024 + t * 4;
    int v[4]; int s = 0;
#pragma unroll
    for (int u = 0; u < 4; ++u) {
        int i = base + u;
        v[u] = (i < NN) ? hist[i] : 0;
        s += v[u];
    }
    sd[t] = s;
    __syncthreads();
    for (int off = 1; off < 256; off <<= 1) {
        int a = (t >= off) ? sd[t - off] : 0;
        __syncthreads();
        sd[t] += a;
        __syncthreads();
    }
    int texcl = sd[t] - s;
    int o = boff[b] + texcl;
#pragma unroll
    for (int u = 0; u < 4; ++u) {
        int i = base + u;
        if (i < NN) rowst[i] = o;
        o += v[u];
    }
}

// ---------------- CSR fill: direct 16B pack scatter (known wall ~84us) ----------------
__global__ __launch_bounds__(256) void fill_kernel(const int* __restrict__ ei,
                                                   const float* __restrict__ ea,
                                                   const int* __restrict__ rowst,
                                                   int* __restrict__ fill,
                                                   float4* __restrict__ pack,
                                                   int padded) {
    const int T = FILL_NB * 256;                 // 524288 threads total
    int t0 = blockIdx.x * 256 + threadIdx.x;
    int e[3] = { t0, t0 + T, t0 + 2 * T };
    int d[3]; float4 p[3]; bool v[3];
#pragma unroll
    for (int u = 0; u < 3; ++u) {
        v[u] = (e[u] < EE);
        if (v[u]) {
            int s = ei[e[u]];
            d[u] = ei[EE + e[u]];
            p[u].x = ea[e[u] * 3 + 0];
            p[u].y = ea[e[u] * 3 + 1];
            p[u].z = ea[e[u] * 3 + 2];
            p[u].w = __int_as_float(s);
        }
    }
    int pos[3];
#pragma unroll
    for (int u = 0; u < 3; ++u)
        if (v[u]) pos[u] = atomicAdd(&fill[d[u]], 1);
#pragma unroll
    for (int u = 0; u < 3; ++u) {
        if (v[u]) {
            if (padded) {
                if (pos[u] < PSTR) pack[((size_t)d[u] << 6) + pos[u]] = p[u];
            } else {
                pack[rowst[d[u]] + pos[u]] = p[u];
            }
        }
    }
}

// ---------------- weighted degree: 16-lane group per node, parallel row-sum ----------------
__global__ __launch_bounds__(256) void degdinv_kernel(const float4* __restrict__ pack,
                                                      const int* __restrict__ rowst,
                                                      const int* __restrict__ cnt,
                                                      float* __restrict__ dinv,
                                                      int padded) {
    int n   = (blockIdx.x * 256 + threadIdx.x) >> 4;
    int sub = threadIdx.x & 15;
    if (n >= NN) return;
    int s0 = padded ? (n << 6) : rowst[n];
    int c  = padded ? min(cnt[n], PSTR) : (rowst[n + 1] - rowst[n]);
    float d0 = 0.f, d1 = 0.f, d2 = 0.f;
    for (int s = sub; s < c; s += 16) {
        float4 p = pack[s0 + s];
        d0 += p.x; d1 += p.y; d2 += p.z;
    }
#pragma unroll
    for (int off = 8; off > 0; off >>= 1) {
        d0 += __shfl_down(d0, off, 16);
        d1 += __shfl_down(d1, off, 16);
        d2 += __shfl_down(d2, off, 16);
    }
    if (sub == 0) {
        d0 += 1.0f; d1 += 1.0f; d2 += 1.0f;   // self-loop weight 1
        dinv[n]          = 1.0f / sqrtf(d0);
        dinv[NN + n]     = 1.0f / sqrtf(d1);
        dinv[2 * NN + n] = 1.0f / sqrtf(d2);
    }
}

// ---------------- fold SOURCE-side dinv into pack (dst side applied in agg) ----------------
__global__ __launch_bounds__(256) void normpack_kernel(const float* __restrict__ dinv,
                                                       const int* __restrict__ rowst,
                                                       const int* __restrict__ cnt,
                                                       float4* __restrict__ pack,
                                                       int padded) {
    int n   = (blockIdx.x * 256 + threadIdx.x) >> 4;
    int sub = threadIdx.x & 15;
    if (n >= NN) return;
    int s0 = padded ? (n << 6) : rowst[n];
    int c  = padded ? min(cnt[n], PSTR) : (rowst[n + 1] - rowst[n]);
    for (int s = sub; s < c; s += 16) {
        float4 p = pack[s0 + s];
        int src = __float_as_int(p.w);
        p.x *= dinv[src];
        p.y *= dinv[NN + src];
        p.z *= dinv[2 * NN + src];
        pack[s0 + s] = p;
    }
}

// ---------------- aggregation: one wave per node, branch-free masked 8-batches ----------------
// R6-proven form: depth-8 x high occupancy beats depth-16 x low occupancy (R11 lesson).
__global__ __launch_bounds__(256) void agg_kernel(const float* __restrict__ h,
                                                  const float4* __restrict__ pack,
                                                  const int* __restrict__ rowst,
                                                  const int* __restrict__ cnt,
                                                  const float* __restrict__ dinv,
                                                  float* __restrict__ agg,
                                                  int padded) {
    int n = (blockIdx.x * 256 + threadIdx.x) >> 6;
    int lane = threadIdx.x & 63;
    if (n >= NN) return;
    float d0 = dinv[n], d1 = dinv[NN + n], d2 = dinv[2 * NN + n];
    float hs = h[(size_t)n * 64 + lane];
    float a0 = hs * d0;     // self-loop: src-side factor = dinv_k[n]
    float a1 = hs * d1;
    float a2 = hs * d2;
    int s0 = padded ? (n << 6) : rowst[n];
    int s1 = s0 + (padded ? min(cnt[n], PSTR) : (rowst[n + 1] - rowst[n]));
    for (int s = s0; s < s1; s += 8) {
        float4 p[8];
#pragma unroll
        for (int u = 0; u < 8; ++u) {
            int idx = s + u;
            p[u] = pack[(idx < s1) ? idx : s0];
        }
        float hv[8];
#pragma unroll
        for (int u = 0; u < 8; ++u)
            hv[u] = h[(size_t)__float_as_int(p[u].w) * 64 + lane];
#pragma unroll
        for (int u = 0; u < 8; ++u) {
            float m = (s + u < s1) ? 1.f : 0.f;
            a0 = fmaf(hv[u], p[u].x * m, a0);
            a1 = fmaf(hv[u], p[u].y * m, a1);
            a2 = fmaf(hv[u], p[u].z * m, a2);
        }
    }
    agg[(size_t)n * 192 + lane]       = a0 * d0;
    agg[(size_t)n * 192 + 64 + lane]  = a1 * d1;
    agg[(size_t)n * 192 + 128 + lane] = a2 * d2;
}

// ---------------- GEMM with register-prefetch double-buffered staging ----------------
// h_new = relu?(agg[N,192]@Wcat[192,64] + bsum) + h
// kc+1's agg/W global loads issue right after kc's LDS write -> latency hides
// under the 64-iteration FMA loop (T14 issue-early/write-late).
__global__ __launch_bounds__(256) void gemm_kernel(const float* __restrict__ agg,
                                                   const float* __restrict__ convW,
                                                   const float* __restrict__ convb,
                                                   float* __restrict__ h,
                                                   int layer, int dorelu) {
    __shared__ float an[64][68];    // agg chunk [node][k]   (+pad)
    __shared__ float ws[64][64];    // W chunk   [k][col]
    int t = threadIdx.x;
    int n0 = blockIdx.x * 64;
    const float* W = convW + (size_t)layer * 192 * 64;
    const float* B = convb + (size_t)layer * 192;
    int nb = t >> 4, cb = t & 15;
    float acc[4][4] = {{0.f}};

    float fa[16], fw[16];
    // prefetch kc=0
#pragma unroll
    for (int rep = 0; rep < 16; ++rep) {
        int flat = rep * 256 + t;
        int r = flat >> 6, i = flat & 63;
        int n = n0 + r;
        fa[rep] = (n < NN) ? agg[(size_t)n * 192 + i] : 0.f;
        fw[rep] = W[flat];
    }

    for (int kc = 0; kc < 3; ++kc) {
        __syncthreads();                 // previous compute done reading LDS
#pragma unroll
        for (int rep = 0; rep < 16; ++rep) {
            int flat = rep * 256 + t;
            int r = flat >> 6, i = flat & 63;
            an[r][i] = fa[rep];
            ((float*)ws)[flat] = fw[rep];
        }
        __syncthreads();
        if (kc < 2) {                    // issue next chunk's loads NOW
#pragma unroll
            for (int rep = 0; rep < 16; ++rep) {
                int flat = rep * 256 + t;
                int r = flat >> 6, i = flat & 63;
                int n = n0 + r;
                fa[rep] = (n < NN) ? agg[(size_t)n * 192 + (kc + 1) * 64 + i] : 0.f;
                fw[rep] = W[(kc + 1) * 4096 + flat];
            }
        }
#pragma unroll 4
        for (int i = 0; i < 64; ++i) {
            float4 wv = *(const float4*)&ws[i][cb * 4];
#pragma unroll
            for (int r = 0; r < 4; ++r) {
                float a = an[nb * 4 + r][i];
                acc[r][0] = fmaf(a, wv.x, acc[r][0]);
                acc[r][1] = fmaf(a, wv.y, acc[r][1]);
                acc[r][2] = fmaf(a, wv.z, acc[r][2]);
                acc[r][3] = fmaf(a, wv.w, acc[r][3]);
            }
        }
    }

    int col0 = cb * 4;
    float bs[4];
#pragma unroll
    for (int c = 0; c < 4; ++c) {
        int col = col0 + c;
        bs[c] = B[col] + B[64 + col] + B[128 + col];
    }
#pragma unroll
    for (int r = 0; r < 4; ++r) {
        int n = n0 + nb * 4 + r;
        if (n < NN) {
            float4 hv = *(const float4*)&h[(size_t)n * 64 + col0];
            float v0 = acc[r][0] + bs[0];
            float v1 = acc[r][1] + bs[1];
            float v2 = acc[r][2] + bs[2];
            float v3 = acc[r][3] + bs[3];
            if (dorelu) {
                v0 = fmaxf(v0, 0.f); v1 = fmaxf(v1, 0.f);
                v2 = fmaxf(v2, 0.f); v3 = fmaxf(v3, 0.f);
            }
            float4 o;
            o.x = v0 + hv.x; o.y = v1 + hv.y; o.z = v2 + hv.z; o.w = v3 + hv.w;
            *(float4*)&h[(size_t)n * 64 + col0] = o;
        }
    }
}

// ---------------- graph start offsets via binary search (batch is sorted) ----------------
__global__ __launch_bounds__(256) void gstart_kernel(const int* __restrict__ batch,
                                                     int* __restrict__ gstart) {
    int g = blockIdx.x * 256 + threadIdx.x;
    if (g > GG) return;
    int lo = 0, hi = NN;
    while (lo < hi) {
        int mid = (lo + hi) >> 1;
        if (batch[mid] < g) lo = mid + 1; else hi = mid;
    }
    gstart[g] = lo;
}

// ---------------- mean pool: one block (4 waves) per graph ----------------
__global__ __launch_bounds__(256) void pool_kernel(const float* __restrict__ h,
                                                   const int* __restrict__ gstart,
                                                   float* __restrict__ hg) {
    __shared__ float red[3][64];
    int g = blockIdx.x;
    int w = threadIdx.x >> 6, lane = threadIdx.x & 63;
    int s = gstart[g], e = gstart[g + 1];
    float sum = 0.f;
    for (int n = s + w; n < e; n += 4) sum += h[(size_t)n * 64 + lane];
    if (w) red[w - 1][lane] = sum;
    __syncthreads();
    if (w == 0) {
        sum += red[0][lane] + red[1][lane] + red[2][lane];
        int c = e - s;
        hg[(size_t)g * 64 + lane] = sum / (float)(c > 0 ? c : 1);
    }
}

// ---------------- fc: 3 stacked linears, one wave per graph ----------------
__global__ __launch_bounds__(256) void fc_kernel(const float* __restrict__ hg,
                                                 const float* __restrict__ W1, const float* __restrict__ b1,
                                                 const float* __restrict__ W2, const float* __restrict__ b2,
                                                 const float* __restrict__ W3, const float* __restrict__ b3,
                                                 float* __restrict__ out) {
    int g = (blockIdx.x * 256 + threadIdx.x) >> 6;
    int lane = threadIdx.x & 63;
    if (g >= GG) return;
    float x = hg[(size_t)g * 64 + lane];
    float t1 = b1[lane];
    for (int i = 0; i < 64; ++i) t1 = fmaf(__shfl(x, i, 64), W1[i * 64 + lane], t1);
    float t2 = b2[lane];
    for (int i = 0; i < 64; ++i) t2 = fmaf(__shfl(t1, i, 64), W2[i * 64 + lane], t2);
    float p = t2 * W3[lane];
    for (int off = 32; off > 0; off >>= 1) p += __shfl_down(p, off, 64);
    if (lane == 0) out[g] = p + b3[0];
}

extern "C" void kernel_launch(void* const* d_in, const int* in_sizes, int n_in,
                              void* d_out, int out_size, void* d_ws, size_t ws_size,
                              hipStream_t stream) {
    const int*   x_atom = (const int*)d_in[0];
    const int*   ei     = (const int*)d_in[1];
    const float* ea     = (const float*)d_in[2];
    const int*   batch  = (const int*)d_in[3];
    const float* emb    = (const float*)d_in[4];
    const float* convW  = (const float*)d_in[5];
    const float* convb  = (const float*)d_in[6];
    const float* W1 = (const float*)d_in[7];  const float* b1 = (const float*)d_in[8];
    const float* W2 = (const float*)d_in[9];  const float* b2 = (const float*)d_in[10];
    const float* W3 = (const float*)d_in[11]; const float* b3 = (const float*)d_in[12];
    float* out = (float*)d_out;

    char* p = (char*)d_ws;
    size_t used = 0;
    auto alloc = [&](size_t bytes) -> void* {
        void* r = (void*)p;
        size_t rb = (bytes + 255) & ~(size_t)255;
        p += rb; used += rb;
        return r;
    };
    float*  h     = (float*)alloc((size_t)NN * 64 * 4);       // 25.6 MB
    float*  agg   = (float*)alloc((size_t)NN * 192 * 4);      // 76.8 MB
    float*  dinv  = (float*)alloc((size_t)3 * NN * 4);        // 1.2 MB
    int*    hist  = (int*)alloc((size_t)NN * 4);
    int*    rowst = (int*)alloc((size_t)(NN + 1) * 4);
    int*    fill  = (int*)alloc((size_t)NN * 4);
    int*    bsum  = (int*)alloc(128 * 4);
    int*    boff  = (int*)alloc(128 * 4);
    int*    gstart= (int*)alloc((size_t)(GG + 1) * 4);
    float*  hg    = (float*)alloc((size_t)GG * 64 * 4);
    // pack last: padded (102.4 MB) if workspace allows, else compact (19.2 MB, +8 slot margin)
    size_t padded_pack  = (size_t)NN * PSTR * 16;
    size_t compact_pack = (size_t)(EE + 8) * 16;
    int padded = (ws_size >= used + padded_pack) ? 1 : 0;
    float4* pack = (float4*)alloc(padded ? padded_pack : compact_pack);

    // ---- encoder + CSR build ----
    enc_kernel<<<(NN * 64) / 256, 256, 0, stream>>>(x_atom, emb, h);
    init_kernel<<<(NN + 255) / 256, 256, 0, stream>>>(hist, fill);
    if (!padded) {
        hist_kernel<<<(EE + 255) / 256, 256, 0, stream>>>(ei, hist);
        scan1_kernel<<<SCAN_NB, 256, 0, stream>>>(hist, bsum);
        scan2_kernel<<<1, 64, 0, stream>>>(bsum, boff, rowst);
        scan3_kernel<<<SCAN_NB, 256, 0, stream>>>(hist, boff, rowst);
    }
    fill_kernel<<<FILL_NB, 256, 0, stream>>>(ei, ea, rowst, fill, pack, padded);
    degdinv_kernel<<<(NN * 16 + 255) / 256, 256, 0, stream>>>(pack, rowst, fill, dinv, padded);
    normpack_kernel<<<(NN * 16 + 255) / 256, 256, 0, stream>>>(dinv, rowst, fill, pack, padded);
    gstart_kernel<<<(GG + 1 + 255) / 256, 256, 0, stream>>>(batch, gstart);

    // ---- 3 GCN layers: aggregate-then-GEMM (linearity refactor) ----
    for (int layer = 0; layer < LL; ++layer) {
        agg_kernel<<<NN / 4, 256, 0, stream>>>(h, pack, rowst, fill, dinv, agg, padded);
        gemm_kernel<<<(NN + 63) / 64, 256, 0, stream>>>(agg, convW, convb, h, layer,
                                                        (layer < LL - 1) ? 1 : 0);
    }

    // ---- pool + fc ----
    pool_kernel<<<GG, 256, 0, stream>>>(h, gstart, hg);
    fc_kernel<<<GG / 4, 256, 0, stream>>>(hg, W1, b1, W2, b2, W3, b3, out);
}

// Round 13
// 463.715 us; speedup vs baseline: 1.3151x; 1.0522x over previous
//
#include <hip/hip_runtime.h>
#include <hip/hip_fp16.h>
#include <math.h>

#define NN 100000
#define EE 1200000
#define DD 64
#define GG 1024
#define LL 3
#define VOCAB 128
#define SCAN_NB 98     // ceil(100000/1024)
#define PSTR 64        // padded CSR row stride (slots/node); Poisson(12) max-deg << 64
#define FILL_NB 2048   // fill grid: 8 blocks/CU

// ---------------- encoder: h[n][j] = sum_f emb[f][x_atom[n][f]][j] (+ fp16 shadow) ----------------
__global__ __launch_bounds__(256) void enc_kernel(const int* __restrict__ x_atom,
                                                  const float* __restrict__ emb,
                                                  float* __restrict__ h,
                                                  __half* __restrict__ h16) {
    int idx = blockIdx.x * 256 + threadIdx.x;      // n*64 + j
    if (idx >= NN * 64) return;
    int n = idx >> 6, j = idx & 63;
    int v0 = x_atom[n * 3 + 0];
    int v1 = x_atom[n * 3 + 1];
    int v2 = x_atom[n * 3 + 2];
    float v = emb[(0 * VOCAB + v0) * 64 + j]
            + emb[(1 * VOCAB + v1) * 64 + j]
            + emb[(2 * VOCAB + v2) * 64 + j];
    h[idx] = v;
    h16[idx] = __float2half(v);
}

// ---------------- init: hist=0, fill=0 ----------------
__global__ __launch_bounds__(256) void init_kernel(int* __restrict__ hist,
                                                   int* __restrict__ fill) {
    int i = blockIdx.x * 256 + threadIdx.x;
    if (i < NN) { hist[i] = 0; fill[i] = 0; }
}

// ---------------- in-degree histogram (compact fallback path only) ----------------
__global__ __launch_bounds__(256) void hist_kernel(const int* __restrict__ ei,
                                                   int* __restrict__ hist) {
    int e = blockIdx.x * 256 + threadIdx.x;
    if (e >= EE) return;
    atomicAdd(&hist[ei[EE + e]], 1);
}

// ---------------- scan stage 1 (fallback) ----------------
__global__ __launch_bounds__(256) void scan1_kernel(const int* __restrict__ hist,
                                                    int* __restrict__ bsum) {
    __shared__ int sd[256];
    int t = threadIdx.x, b = blockIdx.x;
    int base = b * 1024 + t * 4;
    int s = 0;
#pragma unroll
    for (int u = 0; u < 4; ++u) { int i = base + u; if (i < NN) s += hist[i]; }
    sd[t] = s;
    __syncthreads();
    for (int off = 128; off > 0; off >>= 1) {
        if (t < off) sd[t] += sd[t + off];
        __syncthreads();
    }
    if (t == 0) bsum[b] = sd[0];
}

// ---------------- scan stage 2 (fallback) ----------------
__global__ void scan2_kernel(const int* __restrict__ bsum, int* __restrict__ boff,
                             int* __restrict__ rowst) {
    if (threadIdx.x == 0 && blockIdx.x == 0) {
        int acc = 0;
        for (int i = 0; i < SCAN_NB; ++i) { boff[i] = acc; acc += bsum[i]; }
        rowst[NN] = acc;   // == EE
    }
}

// ---------------- scan stage 3 (fallback) ----------------
__global__ __launch_bounds__(256) void scan3_kernel(const int* __restrict__ hist,
                                                    const int* __restrict__ boff,
                                                    int* __restrict__ rowst) {
    __shared__ int sd[256];
    int t = threadIdx.x, b = blockIdx.x;
    int base = b * 1024 + t * 4;
    int v[4]; int s = 0;
#pragma unroll
    for (int u = 0; u < 4; ++u) {
        int i = base + u;
        v[u] = (i < NN) ? hist[i] : 0;
        s += v[u];
    }
    sd[t] = s;
    __syncthreads();
    for (int off = 1; off < 256; off <<= 1) {
        int a = (t >= off) ? sd[t - off] : 0;
        __syncthreads();
        sd[t] += a;
        __syncthreads();
    }
    int texcl = sd[t] - s;
    int o = boff[b] + texcl;
#pragma unroll
    for (int u = 0; u < 4; ++u) {
        int i = base + u;
        if (i < NN) rowst[i] = o;
        o += v[u];
    }
}

// ---------------- CSR fill: direct 16B pack scatter (known wall ~84us) ----------------
__global__ __launch_bounds__(256) void fill_kernel(const int* __restrict__ ei,
                                                   const float* __restrict__ ea,
                                                   const int* __restrict__ rowst,
                                                   int* __restrict__ fill,
                                                   float4* __restrict__ pack,
                                                   int padded) {
    const int T = FILL_NB * 256;                 // 524288 threads total
    int t0 = blockIdx.x * 256 + threadIdx.x;
    int e[3] = { t0, t0 + T, t0 + 2 * T };
    int d[3]; float4 p[3]; bool v[3];
#pragma unroll
    for (int u = 0; u < 3; ++u) {
        v[u] = (e[u] < EE);
        if (v[u]) {
            int s = ei[e[u]];
            d[u] = ei[EE + e[u]];
            p[u].x = ea[e[u] * 3 + 0];
            p[u].y = ea[e[u] * 3 + 1];
            p[u].z = ea[e[u] * 3 + 2];
            p[u].w = __int_as_float(s);
        }
    }
    int pos[3];
#pragma unroll
    for (int u = 0; u < 3; ++u)
        if (v[u]) pos[u] = atomicAdd(&fill[d[u]], 1);
#pragma unroll
    for (int u = 0; u < 3; ++u) {
        if (v[u]) {
            if (padded) {
                if (pos[u] < PSTR) pack[((size_t)d[u] << 6) + pos[u]] = p[u];
            } else {
                pack[rowst[d[u]] + pos[u]] = p[u];
            }
        }
    }
}

// ---------------- weighted degree: 16-lane group per node, parallel row-sum ----------------
__global__ __launch_bounds__(256) void degdinv_kernel(const float4* __restrict__ pack,
                                                      const int* __restrict__ rowst,
                                                      const int* __restrict__ cnt,
                                                      float* __restrict__ dinv,
                                                      int padded) {
    int n   = (blockIdx.x * 256 + threadIdx.x) >> 4;
    int sub = threadIdx.x & 15;
    if (n >= NN) return;
    int s0 = padded ? (n << 6) : rowst[n];
    int c  = padded ? min(cnt[n], PSTR) : (rowst[n + 1] - rowst[n]);
    float d0 = 0.f, d1 = 0.f, d2 = 0.f;
    for (int s = sub; s < c; s += 16) {
        float4 p = pack[s0 + s];
        d0 += p.x; d1 += p.y; d2 += p.z;
    }
#pragma unroll
    for (int off = 8; off > 0; off >>= 1) {
        d0 += __shfl_down(d0, off, 16);
        d1 += __shfl_down(d1, off, 16);
        d2 += __shfl_down(d2, off, 16);
    }
    if (sub == 0) {
        d0 += 1.0f; d1 += 1.0f; d2 += 1.0f;   // self-loop weight 1
        dinv[n]          = 1.0f / sqrtf(d0);
        dinv[NN + n]     = 1.0f / sqrtf(d1);
        dinv[2 * NN + n] = 1.0f / sqrtf(d2);
    }
}

// ---------------- fold SOURCE-side dinv into pack (dst side applied in agg) ----------------
__global__ __launch_bounds__(256) void normpack_kernel(const float* __restrict__ dinv,
                                                       const int* __restrict__ rowst,
                                                       const int* __restrict__ cnt,
                                                       float4* __restrict__ pack,
                                                       int padded) {
    int n   = (blockIdx.x * 256 + threadIdx.x) >> 4;
    int sub = threadIdx.x & 15;
    if (n >= NN) return;
    int s0 = padded ? (n << 6) : rowst[n];
    int c  = padded ? min(cnt[n], PSTR) : (rowst[n + 1] - rowst[n]);
    for (int s = sub; s < c; s += 16) {
        float4 p = pack[s0 + s];
        int src = __float_as_int(p.w);
        p.x *= dinv[src];
        p.y *= dinv[NN + src];
        p.z *= dinv[2 * NN + src];
        pack[s0 + s] = p;
    }
}

// ---------------- aggregation: one wave per node, masked 8-batches, fp16 gathers ----------------
// Neighbor rows read from the fp16 shadow (128B = 2 lines vs 4); self-loop stays fp32.
__global__ __launch_bounds__(256) void agg_kernel(const float* __restrict__ h,
                                                  const __half* __restrict__ h16,
                                                  const float4* __restrict__ pack,
                                                  const int* __restrict__ rowst,
                                                  const int* __restrict__ cnt,
                                                  const float* __restrict__ dinv,
                                                  float* __restrict__ agg,
                                                  int padded) {
    int n = (blockIdx.x * 256 + threadIdx.x) >> 6;
    int lane = threadIdx.x & 63;
    if (n >= NN) return;
    float d0 = dinv[n], d1 = dinv[NN + n], d2 = dinv[2 * NN + n];
    float hs = h[(size_t)n * 64 + lane];
    float a0 = hs * d0;     // self-loop: src-side factor = dinv_k[n]  (exact fp32)
    float a1 = hs * d1;
    float a2 = hs * d2;
    int s0 = padded ? (n << 6) : rowst[n];
    int s1 = s0 + (padded ? min(cnt[n], PSTR) : (rowst[n + 1] - rowst[n]));
    for (int s = s0; s < s1; s += 8) {
        float4 p[8];
#pragma unroll
        for (int u = 0; u < 8; ++u) {
            int idx = s + u;
            p[u] = pack[(idx < s1) ? idx : s0];
        }
        float hv[8];
#pragma unroll
        for (int u = 0; u < 8; ++u)
            hv[u] = __half2float(h16[(size_t)__float_as_int(p[u].w) * 64 + lane]);
#pragma unroll
        for (int u = 0; u < 8; ++u) {
            float m = (s + u < s1) ? 1.f : 0.f;
            a0 = fmaf(hv[u], p[u].x * m, a0);
            a1 = fmaf(hv[u], p[u].y * m, a1);
            a2 = fmaf(hv[u], p[u].z * m, a2);
        }
    }
    agg[(size_t)n * 192 + lane]       = a0 * d0;
    agg[(size_t)n * 192 + 64 + lane]  = a1 * d1;
    agg[(size_t)n * 192 + 128 + lane] = a2 * d2;
}

// ---------------- GEMM with register-prefetch double-buffered staging (+ h16 shadow write) ----
__global__ __launch_bounds__(256) void gemm_kernel(const float* __restrict__ agg,
                                                   const float* __restrict__ convW,
                                                   const float* __restrict__ convb,
                                                   float* __restrict__ h,
                                                   __half* __restrict__ h16,
                                                   int layer, int dorelu) {
    __shared__ float an[64][68];    // agg chunk [node][k]   (+pad)
    __shared__ float ws[64][64];    // W chunk   [k][col]
    int t = threadIdx.x;
    int n0 = blockIdx.x * 64;
    const float* W = convW + (size_t)layer * 192 * 64;
    const float* B = convb + (size_t)layer * 192;
    int nb = t >> 4, cb = t & 15;
    float acc[4][4] = {{0.f}};

    float fa[16], fw[16];
    // prefetch kc=0
#pragma unroll
    for (int rep = 0; rep < 16; ++rep) {
        int flat = rep * 256 + t;
        int r = flat >> 6, i = flat & 63;
        int n = n0 + r;
        fa[rep] = (n < NN) ? agg[(size_t)n * 192 + i] : 0.f;
        fw[rep] = W[flat];
    }

    for (int kc = 0; kc < 3; ++kc) {
        __syncthreads();                 // previous compute done reading LDS
#pragma unroll
        for (int rep = 0; rep < 16; ++rep) {
            int flat = rep * 256 + t;
            int r = flat >> 6, i = flat & 63;
            an[r][i] = fa[rep];
            ((float*)ws)[flat] = fw[rep];
        }
        __syncthreads();
        if (kc < 2) {                    // issue next chunk's loads NOW
#pragma unroll
            for (int rep = 0; rep < 16; ++rep) {
                int flat = rep * 256 + t;
                int r = flat >> 6, i = flat & 63;
                int n = n0 + r;
                fa[rep] = (n < NN) ? agg[(size_t)n * 192 + (kc + 1) * 64 + i] : 0.f;
                fw[rep] = W[(kc + 1) * 4096 + flat];
            }
        }
#pragma unroll 4
        for (int i = 0; i < 64; ++i) {
            float4 wv = *(const float4*)&ws[i][cb * 4];
#pragma unroll
            for (int r = 0; r < 4; ++r) {
                float a = an[nb * 4 + r][i];
                acc[r][0] = fmaf(a, wv.x, acc[r][0]);
                acc[r][1] = fmaf(a, wv.y, acc[r][1]);
                acc[r][2] = fmaf(a, wv.z, acc[r][2]);
                acc[r][3] = fmaf(a, wv.w, acc[r][3]);
            }
        }
    }

    int col0 = cb * 4;
    float bs[4];
#pragma unroll
    for (int c = 0; c < 4; ++c) {
        int col = col0 + c;
        bs[c] = B[col] + B[64 + col] + B[128 + col];
    }
#pragma unroll
    for (int r = 0; r < 4; ++r) {
        int n = n0 + nb * 4 + r;
        if (n < NN) {
            float4 hv = *(const float4*)&h[(size_t)n * 64 + col0];
            float v0 = acc[r][0] + bs[0];
            float v1 = acc[r][1] + bs[1];
            float v2 = acc[r][2] + bs[2];
            float v3 = acc[r][3] + bs[3];
            if (dorelu) {
                v0 = fmaxf(v0, 0.f); v1 = fmaxf(v1, 0.f);
                v2 = fmaxf(v2, 0.f); v3 = fmaxf(v3, 0.f);
            }
            float4 o;
            o.x = v0 + hv.x; o.y = v1 + hv.y; o.z = v2 + hv.z; o.w = v3 + hv.w;
            *(float4*)&h[(size_t)n * 64 + col0] = o;
            union { __half hh[4]; unsigned long long u; } pk;
            pk.hh[0] = __float2half(o.x);
            pk.hh[1] = __float2half(o.y);
            pk.hh[2] = __float2half(o.z);
            pk.hh[3] = __float2half(o.w);
            *(unsigned long long*)&h16[(size_t)n * 64 + col0] = pk.u;
        }
    }
}

// ---------------- graph start offsets via binary search (batch is sorted) ----------------
__global__ __launch_bounds__(256) void gstart_kernel(const int* __restrict__ batch,
                                                     int* __restrict__ gstart) {
    int g = blockIdx.x * 256 + threadIdx.x;
    if (g > GG) return;
    int lo = 0, hi = NN;
    while (lo < hi) {
        int mid = (lo + hi) >> 1;
        if (batch[mid] < g) lo = mid + 1; else hi = mid;
    }
    gstart[g] = lo;
}

// ---------------- mean pool: one block (4 waves) per graph ----------------
__global__ __launch_bounds__(256) void pool_kernel(const float* __restrict__ h,
                                                   const int* __restrict__ gstart,
                                                   float* __restrict__ hg) {
    __shared__ float red[3][64];
    int g = blockIdx.x;
    int w = threadIdx.x >> 6, lane = threadIdx.x & 63;
    int s = gstart[g], e = gstart[g + 1];
    float sum = 0.f;
    for (int n = s + w; n < e; n += 4) sum += h[(size_t)n * 64 + lane];
    if (w) red[w - 1][lane] = sum;
    __syncthreads();
    if (w == 0) {
        sum += red[0][lane] + red[1][lane] + red[2][lane];
        int c = e - s;
        hg[(size_t)g * 64 + lane] = sum / (float)(c > 0 ? c : 1);
    }
}

// ---------------- fc: 3 stacked linears, one wave per graph ----------------
__global__ __launch_bounds__(256) void fc_kernel(const float* __restrict__ hg,
                                                 const float* __restrict__ W1, const float* __restrict__ b1,
                                                 const float* __restrict__ W2, const float* __restrict__ b2,
                                                 const float* __restrict__ W3, const float* __restrict__ b3,
                                                 float* __restrict__ out) {
    int g = (blockIdx.x * 256 + threadIdx.x) >> 6;
    int lane = threadIdx.x & 63;
    if (g >= GG) return;
    float x = hg[(size_t)g * 64 + lane];
    float t1 = b1[lane];
    for (int i = 0; i < 64; ++i) t1 = fmaf(__shfl(x, i, 64), W1[i * 64 + lane], t1);
    float t2 = b2[lane];
    for (int i = 0; i < 64; ++i) t2 = fmaf(__shfl(t1, i, 64), W2[i * 64 + lane], t2);
    float p = t2 * W3[lane];
    for (int off = 32; off > 0; off >>= 1) p += __shfl_down(p, off, 64);
    if (lane == 0) out[g] = p + b3[0];
}

extern "C" void kernel_launch(void* const* d_in, const int* in_sizes, int n_in,
                              void* d_out, int out_size, void* d_ws, size_t ws_size,
                              hipStream_t stream) {
    const int*   x_atom = (const int*)d_in[0];
    const int*   ei     = (const int*)d_in[1];
    const float* ea     = (const float*)d_in[2];
    const int*   batch  = (const int*)d_in[3];
    const float* emb    = (const float*)d_in[4];
    const float* convW  = (const float*)d_in[5];
    const float* convb  = (const float*)d_in[6];
    const float* W1 = (const float*)d_in[7];  const float* b1 = (const float*)d_in[8];
    const float* W2 = (const float*)d_in[9];  const float* b2 = (const float*)d_in[10];
    const float* W3 = (const float*)d_in[11]; const float* b3 = (const float*)d_in[12];
    float* out = (float*)d_out;

    char* p = (char*)d_ws;
    size_t used = 0;
    auto alloc = [&](size_t bytes) -> void* {
        void* r = (void*)p;
        size_t rb = (bytes + 255) & ~(size_t)255;
        p += rb; used += rb;
        return r;
    };
    float*  h     = (float*)alloc((size_t)NN * 64 * 4);       // 25.6 MB
    __half* h16   = (__half*)alloc((size_t)NN * 64 * 2);      // 12.8 MB (gather shadow)
    float*  agg   = (float*)alloc((size_t)NN * 192 * 4);      // 76.8 MB
    float*  dinv  = (float*)alloc((size_t)3 * NN * 4);        // 1.2 MB
    int*    hist  = (int*)alloc((size_t)NN * 4);
    int*    rowst = (int*)alloc((size_t)(NN + 1) * 4);
    int*    fill  = (int*)alloc((size_t)NN * 4);
    int*    bsum  = (int*)alloc(128 * 4);
    int*    boff  = (int*)alloc(128 * 4);
    int*    gstart= (int*)alloc((size_t)(GG + 1) * 4);
    float*  hg    = (float*)alloc((size_t)GG * 64 * 4);
    // pack last: padded (102.4 MB) if workspace allows, else compact (19.2 MB, +8 slot margin)
    size_t padded_pack  = (size_t)NN * PSTR * 16;
    size_t compact_pack = (size_t)(EE + 8) * 16;
    int padded = (ws_size >= used + padded_pack) ? 1 : 0;
    float4* pack = (float4*)alloc(padded ? padded_pack : compact_pack);

    // ---- encoder + CSR build ----
    enc_kernel<<<(NN * 64) / 256, 256, 0, stream>>>(x_atom, emb, h, h16);
    init_kernel<<<(NN + 255) / 256, 256, 0, stream>>>(hist, fill);
    if (!padded) {
        hist_kernel<<<(EE + 255) / 256, 256, 0, stream>>>(ei, hist);
        scan1_kernel<<<SCAN_NB, 256, 0, stream>>>(hist, bsum);
        scan2_kernel<<<1, 64, 0, stream>>>(bsum, boff, rowst);
        scan3_kernel<<<SCAN_NB, 256, 0, stream>>>(hist, boff, rowst);
    }
    fill_kernel<<<FILL_NB, 256, 0, stream>>>(ei, ea, rowst, fill, pack, padded);
    degdinv_kernel<<<(NN * 16 + 255) / 256, 256, 0, stream>>>(pack, rowst, fill, dinv, padded);
    normpack_kernel<<<(NN * 16 + 255) / 256, 256, 0, stream>>>(dinv, rowst, fill, pack, padded);
    gstart_kernel<<<(GG + 1 + 255) / 256, 256, 0, stream>>>(batch, gstart);

    // ---- 3 GCN layers: aggregate-then-GEMM (linearity refactor) ----
    for (int layer = 0; layer < LL; ++layer) {
        agg_kernel<<<NN / 4, 256, 0, stream>>>(h, h16, pack, rowst, fill, dinv, agg, padded);
        gemm_kernel<<<(NN + 63) / 64, 256, 0, stream>>>(agg, convW, convb, h, h16, layer,
                                                        (layer < LL - 1) ? 1 : 0);
    }

    // ---- pool + fc ----
    pool_kernel<<<GG, 256, 0, stream>>>(h, gstart, hg);
    fc_kernel<<<GG / 4, 256, 0, stream>>>(hg, W1, b1, W2, b2, W3, b3, out);
}